// Round 1
// baseline (120.523 us; speedup 1.0000x reference)
//
#include <hip/hip_runtime.h>
#include <cstdint>
#include <cstddef>

#define BB 4
#define NN 16384
#define SS 4096
#define CC 64
#define NSAMP 64
// radius*radius computed in python double (0.04000000000000000083),
// cast to f32 at the comparison -> 0.04f
#define R2 0.04f

// ---------------------------------------------------------------------------
// Kernel 1: transpose features (B,C,N) -> featT (B,N,C) in workspace.
// 64x64 tiles via LDS, stride-65 padding (2-way bank aliasing = free).
// ---------------------------------------------------------------------------
__global__ __launch_bounds__(256) void transpose_feat(const float* __restrict__ f,
                                                      float* __restrict__ ft) {
    __shared__ float tile[64][65];
    int blk = blockIdx.x;              // b * (N/64) + ntile
    int b   = blk / (NN / 64);
    int n0  = (blk % (NN / 64)) * 64;
    int t   = threadIdx.x;
    int nl  = t & 63;                  // 0..63
    int cq  = t >> 6;                  // 0..3
#pragma unroll
    for (int p = 0; p < 16; ++p) {
        int c = cq + p * 4;
        tile[c][nl] = f[((size_t)b * CC + c) * NN + n0 + nl];   // coalesced read
    }
    __syncthreads();
#pragma unroll
    for (int p = 0; p < 16; ++p) {
        int nl2 = cq + p * 4;
        // ft[b][n0+nl2][nl] = f[b][nl][n0+nl2]
        ft[((size_t)b * NN + n0 + nl2) * CC + nl] = tile[nl][nl2]; // coalesced write
    }
}

// ---------------------------------------------------------------------------
// Kernel 2: fused ball-query + group. One wave (64 lanes) per query point.
// Ball query: ordered compaction via __ballot + prefix popcount, early exit.
// Group: coalesced featT row gathers -> LDS 64x33 transpose tile -> float4
// coalesced stores. USE_T=0 fallback gathers from original layout.
// ---------------------------------------------------------------------------
template <int USE_T>
__global__ __launch_bounds__(64) void qg_kernel(const float* __restrict__ xyz,
                                                const float* __restrict__ nxyz,
                                                const float* __restrict__ feat,
                                                const float* __restrict__ featT,
                                                float* __restrict__ out) {
    __shared__ float tile[64][33];   // half of the 64x64 feature tile (32 ch)
    __shared__ int   sidx[NSAMP];

    int wg = blockIdx.x;
    // XCD swizzle: 16384 blocks over 8 XCDs; each XCD gets a contiguous
    // half-batch of queries -> its featT working set ~4MB = one XCD L2.
    int q    = (wg & 7) * (BB * SS / 8) + (wg >> 3);
    int b    = q / SS;
    int s    = q % SS;
    int lane = threadIdx.x;

    const float* xb = xyz + (size_t)b * NN * 3;

    float qx = nxyz[((size_t)b * SS + s) * 3 + 0];
    float qy = nxyz[((size_t)b * SS + s) * 3 + 1];
    float qz = nxyz[((size_t)b * SS + s) * 3 + 2];
    // q2 = (qx*qx + qy*qy) + qz*qz  -- numpy f32 sequential, no FMA
    float q2 = __fadd_rn(__fadd_rn(__fmul_rn(qx, qx), __fmul_rn(qy, qy)),
                         __fmul_rn(qz, qz));

    // ---- ball query ----
    int cnt = 0;
    // prefetch first chunk
    float px = xb[(size_t)lane * 3 + 0];
    float py = xb[(size_t)lane * 3 + 1];
    float pz = xb[(size_t)lane * 3 + 2];
    for (int base = 0; base < NN; base += 64) {
        float cx = px, cy = py, cz = pz;
        int nb = base + 64;
        if (nb < NN) {   // uniform branch; prefetch next chunk
            px = xb[(size_t)(nb + lane) * 3 + 0];
            py = xb[(size_t)(nb + lane) * 3 + 1];
            pz = xb[(size_t)(nb + lane) * 3 + 2];
        }
        // p2 = (x*x + y*y) + z*z ; qp = (qx*x + qy*y) + qz*z ; d2 = (q2+p2) - 2*qp
        float p2 = __fadd_rn(__fadd_rn(__fmul_rn(cx, cx), __fmul_rn(cy, cy)),
                             __fmul_rn(cz, cz));
        float qp = __fadd_rn(__fadd_rn(__fmul_rn(qx, cx), __fmul_rn(qy, cy)),
                             __fmul_rn(qz, cz));
        float d2 = __fsub_rn(__fadd_rn(q2, p2), __fadd_rn(qp, qp));
        bool in = d2 < R2;
        unsigned long long m = __ballot(in);
        if (in) {
            int pos = cnt + __popcll(m & ((1ull << lane) - 1ull));
            if (pos < NSAMP) sidx[pos] = base + lane;
        }
        cnt += __popcll(m);
        if (cnt >= NSAMP) break;   // uniform
    }
    __syncthreads();

    int total = cnt < NSAMP ? cnt : NSAMP;
    int myidx;
    if (total == 0) myidx = 0;
    else            myidx = (lane < total) ? sidx[lane] : sidx[0];
    __syncthreads();
    sidx[lane] = myidx;
    __syncthreads();

    // ---- grouped_xyz channels 0..2 ----
    size_t obase   = ((size_t)b * 67) * SS * 64 + (size_t)s * 64;
    size_t chs     = (size_t)SS * 64;   // channel stride
    float gx = __fsub_rn(xb[(size_t)myidx * 3 + 0], qx);
    float gy = __fsub_rn(xb[(size_t)myidx * 3 + 1], qy);
    float gz = __fsub_rn(xb[(size_t)myidx * 3 + 2], qz);
    out[obase + 0 * chs + lane] = gx;
    out[obase + 1 * chs + lane] = gy;
    out[obase + 2 * chs + lane] = gz;

    // ---- grouped features channels 3..66 ----
    if (USE_T) {
        const float* ftb = featT + (size_t)b * NN * CC;
        for (int h = 0; h < 2; ++h) {            // two 32-channel halves
            int rsub = lane >> 3;                // 0..7  (row within 8-row chunk)
            int c4   = lane & 7;                 // 0..7  (float4 col group)
#pragma unroll
            for (int kb = 0; kb < 64; kb += 8) { // 8 rows per iter
                int k   = kb + rsub;
                int row = sidx[k];
                const float4 v = *(const float4*)(ftb + (size_t)row * CC + h * 32 + c4 * 4);
                tile[k][c4 * 4 + 0] = v.x;
                tile[k][c4 * 4 + 1] = v.y;
                tile[k][c4 * 4 + 2] = v.z;
                tile[k][c4 * 4 + 3] = v.w;
            }
            __syncthreads();
            int csub = lane >> 4;                // 0..3
            int k4   = lane & 15;                // 0..15
#pragma unroll
            for (int cb = 0; cb < 32; cb += 4) {
                int c = cb + csub;
                float4 o;
                o.x = tile[k4 * 4 + 0][c];
                o.y = tile[k4 * 4 + 1][c];
                o.z = tile[k4 * 4 + 2][c];
                o.w = tile[k4 * 4 + 3][c];
                *(float4*)(out + obase + (size_t)(3 + h * 32 + c) * chs + k4 * 4) = o;
            }
            __syncthreads();
        }
    } else {
        // fallback: direct gather from (C,N) layout (uncoalesced reads)
        const float* fb = feat + (size_t)b * CC * NN;
#pragma unroll 4
        for (int c = 0; c < CC; ++c) {
            out[obase + (size_t)(3 + c) * chs + lane] = fb[(size_t)c * NN + myidx];
        }
    }
}

// ---------------------------------------------------------------------------
extern "C" void kernel_launch(void* const* d_in, const int* in_sizes, int n_in,
                              void* d_out, int out_size, void* d_ws, size_t ws_size,
                              hipStream_t stream) {
    const float* xyz  = (const float*)d_in[0];   // (B,N,3)
    const float* nxyz = (const float*)d_in[1];   // (B,S,3)
    const float* feat = (const float*)d_in[2];   // (B,C,N)
    float* out = (float*)d_out;                  // (B,67,S,64)

    size_t needT = (size_t)BB * NN * CC * sizeof(float);   // 16 MB
    if (ws_size >= needT) {
        float* featT = (float*)d_ws;
        transpose_feat<<<BB * (NN / 64), 256, 0, stream>>>(feat, featT);
        qg_kernel<1><<<BB * SS, 64, 0, stream>>>(xyz, nxyz, feat, featT, out);
    } else {
        qg_kernel<0><<<BB * SS, 64, 0, stream>>>(xyz, nxyz, feat, nullptr, out);
    }
}